// Round 20
// baseline (71.062 us; speedup 1.0000x reference)
//
#include <hip/hip_runtime.h>

using u16 = unsigned short;
using u32 = unsigned int;
using u64 = unsigned long long;

#define ALPHA 0.2f
#define LOG2E 1.4426950408889634f

typedef __bf16 bf16x8 __attribute__((ext_vector_type(8)));
typedef float f32x4 __attribute__((ext_vector_type(4)));
typedef float f32x16 __attribute__((ext_vector_type(16)));

__device__ __forceinline__ u16 f2bf(float f) {
  u32 u = __builtin_bit_cast(u32, f);
  u += 0x7FFFu + ((u >> 16) & 1u);   // RTNE
  return (u16)(u >> 16);
}
__device__ __forceinline__ float bf2f(u16 h) {
  u32 u = ((u32)h) << 16;
  return __builtin_bit_cast(float, u);
}
__device__ __forceinline__ void gload_lds16(const void* g, void* l) {
  __builtin_amdgcn_global_load_lds((__attribute__((address_space(1))) void*)g,
                                   (__attribute__((address_space(3))) void*)l,
                                   16, 0, 0);
}

// ---------- cast+transpose W: wbt[n][k] = bf16(W[k][n]) ----------
__global__ __launch_bounds__(256) void k_cast_wT(const float* __restrict__ W, u16* __restrict__ wbt) {
  int idx = blockIdx.x * 256 + threadIdx.x;
  int k = idx >> 9, n = idx & 511;
  wbt[n * 512 + k] = f2bf(W[idx]);
}

// ---------- gemm1: h = x@W (M=16384,K=512,N=512). 128x128 tile, 4 waves.
// Triple-buffered, counted vmcnt, XCD-swizzled. Epilogue: hbf + hbt (f-major) + score partials.
__global__ __launch_bounds__(256, 2) void k_gemm1(const float* __restrict__ x, const u16* __restrict__ wbt,
                                                  const float* __restrict__ a,
                                                  u16* __restrict__ hbf, u16* __restrict__ hbt,
                                                  float* __restrict__ s1p, float* __restrict__ s2p) {
  __shared__ __attribute__((aligned(16))) char lds[73728];
  __shared__ __attribute__((aligned(16))) float a_l[256];

  const int t = threadIdx.x;
  const int lane = t & 63;
  const int w = t >> 6;
  const int l31 = lane & 31, lhi = lane >> 5;
  const int rb = w >> 1, cg = w & 1;
  const int g = blockIdx.x;
  const int cb = (g >> 3) & 3;
  const int tile_m = (g & 7) | ((g >> 5) << 3);
  const int row0 = tile_m * 128;
  const int col0 = cb * 128;

  a_l[t] = (t < 128) ? a[col0 + t] : a[512 + col0 + (t - 128)];

  f32x16 acc[2][2];
#pragma unroll
  for (int i = 0; i < 2; ++i)
#pragma unroll
    for (int j = 0; j < 2; ++j)
#pragma unroll
      for (int r = 0; r < 16; ++r) acc[i][j][r] = 0.f;

#define STAGE_G1(kt, Ab, Bb)                                                              \
  {                                                                                       \
    const int k0_ = (kt) * 32;                                                            \
    _Pragma("unroll")                                                                     \
    for (int i = 0; i < 4; ++i) {                                                         \
      int G = i * 256 + t;                                                                \
      int row = G >> 3, ks = G & 7;                                                       \
      gload_lds16(x + (size_t)(row0 + row) * 512 + k0_ + ((ks ^ (row & 7)) * 4),          \
                  (Ab) + (size_t)(i * 256 + w * 64) * 16);                                \
    }                                                                                     \
    _Pragma("unroll")                                                                     \
    for (int i = 0; i < 2; ++i) {                                                         \
      int G = i * 256 + t;                                                                \
      int col = G >> 2, ks = G & 3;                                                       \
      gload_lds16(wbt + (size_t)(col0 + col) * 512 + k0_ + ((ks ^ ((col >> 1) & 3)) * 8), \
                  (Bb) + (size_t)(i * 256 + w * 64) * 16);                                \
    }                                                                                     \
  }

#define COMPUTE_G1(Ab, Bb)                                                                         \
  {                                                                                                \
    _Pragma("unroll")                                                                              \
    for (int ks = 0; ks < 2; ++ks) {                                                               \
      bf16x8 af[2];                                                                                \
      _Pragma("unroll")                                                                            \
      for (int sub = 0; sub < 2; ++sub) {                                                          \
        const int arow = rb * 64 + sub * 32 + l31;                                                 \
        const int kg = ks * 4 + lhi * 2;                                                           \
        f32x4 fa0 = *reinterpret_cast<const f32x4*>((Ab) + (size_t)(arow * 8 + (kg ^ (arow & 7))) * 16); \
        f32x4 fa1 = *reinterpret_cast<const f32x4*>((Ab) + (size_t)(arow * 8 + ((kg + 1) ^ (arow & 7))) * 16); \
        _Pragma("unroll")                                                                          \
        for (int jj = 0; jj < 4; ++jj) {                                                           \
          af[sub][jj] = (__bf16)fa0[jj];                                                           \
          af[sub][jj + 4] = (__bf16)fa1[jj];                                                       \
        }                                                                                          \
      }                                                                                            \
      bf16x8 bfr[2];                                                                               \
      _Pragma("unroll")                                                                            \
      for (int bt = 0; bt < 2; ++bt) {                                                             \
        const int bcol = cg * 64 + bt * 32 + l31;                                                  \
        const int kslot = (ks * 2 + lhi) ^ ((bcol >> 1) & 3);                                      \
        bfr[bt] = *reinterpret_cast<const bf16x8*>((Bb) + (size_t)(bcol * 4 + kslot) * 16);        \
      }                                                                                            \
      _Pragma("unroll")                                                                            \
      for (int sub = 0; sub < 2; ++sub)                                                            \
        _Pragma("unroll")                                                                          \
        for (int bt = 0; bt < 2; ++bt)                                                             \
          acc[sub][bt] = __builtin_amdgcn_mfma_f32_32x32x16_bf16(af[sub], bfr[bt], acc[sub][bt], 0, 0, 0); \
    }                                                                                              \
  }

  char* Ac = lds;             char* Bc = lds + 49152;
  char* An = lds + 16384;     char* Bn = lds + 57344;
  char* As = lds + 32768;     char* Bs = lds + 65536;

  STAGE_G1(0, Ac, Bc);
  STAGE_G1(1, An, Bn);
  __builtin_amdgcn_sched_barrier(0);
  asm volatile("s_waitcnt vmcnt(6) lgkmcnt(0)" ::: "memory");
  __builtin_amdgcn_s_barrier();
  __builtin_amdgcn_sched_barrier(0);

#pragma unroll 1
  for (int kt = 0; kt < 14; ++kt) {
    STAGE_G1(kt + 2, As, Bs);
    COMPUTE_G1(Ac, Bc);
    __builtin_amdgcn_sched_barrier(0);
    asm volatile("s_waitcnt vmcnt(6)" ::: "memory");
    __builtin_amdgcn_s_barrier();
    __builtin_amdgcn_sched_barrier(0);
    char* ta = Ac; Ac = An; An = As; As = ta;
    char* tb = Bc; Bc = Bn; Bn = Bs; Bs = tb;
  }
  COMPUTE_G1(Ac, Bc);
  __builtin_amdgcn_sched_barrier(0);
  asm volatile("s_waitcnt vmcnt(0)" ::: "memory");
  __builtin_amdgcn_s_barrier();
  __builtin_amdgcn_sched_barrier(0);
  COMPUTE_G1(An, Bn);
#undef STAGE_G1
#undef COMPUTE_G1

  __syncthreads();

  u16* lT = (u16*)lds;
#pragma unroll
  for (int sub = 0; sub < 2; ++sub)
#pragma unroll
    for (int bt = 0; bt < 2; ++bt) {
      const int col = cg * 64 + bt * 32 + l31;
#pragma unroll
      for (int r = 0; r < 16; ++r) {
        int row = rb * 64 + sub * 32 + (r & 3) + 8 * (r >> 2) + 4 * lhi;
        lT[row * 136 + col] = f2bf(acc[sub][bt][r]);
      }
    }
  __syncthreads();

  // hbf: [row][col] coalesced (2048 granules)
#pragma unroll
  for (int i = 0; i < 8; ++i) {
    int G = i * 256 + t;
    int row = G >> 4, gg = G & 15;
    uint4 v = *reinterpret_cast<const uint4*>(&lT[row * 136 + gg * 8]);
    *reinterpret_cast<uint4*>(&hbf[(size_t)(row0 + row) * 512 + col0 + gg * 8]) = v;
  }
  // hbt: [b][f][m] (f-major, for sweep2 L1-local gathers)
  const int bb = row0 >> 10;
  const int nb = row0 & 1023;
#pragma unroll
  for (int i = 0; i < 8; ++i) {
    int G = i * 256 + t;
    int col = G & 127, rg = G >> 7;
    u32 wd[4];
#pragma unroll
    for (int jj = 0; jj < 4; ++jj) {
      u16 lo = lT[(rg * 8 + 2 * jj) * 136 + col];
      u16 hi = lT[(rg * 8 + 2 * jj + 1) * 136 + col];
      wd[jj] = (u32)lo | ((u32)hi << 16);
    }
    uint4 o = {wd[0], wd[1], wd[2], wd[3]};
    *reinterpret_cast<uint4*>(&hbt[(size_t)(bb * 512 + col0 + col) * 1024 + nb + rg * 8]) = o;
  }
  // score partials
  {
    const int r2 = t >> 1, half = t & 1;
    float d1 = 0.f, d2 = 0.f;
#pragma unroll
    for (int i = 0; i < 8; ++i) {
      uint4 v = *reinterpret_cast<const uint4*>(&lT[r2 * 136 + half * 64 + i * 8]);
      u32 wds[4] = {v.x, v.y, v.z, v.w};
#pragma unroll
      for (int jj = 0; jj < 8; ++jj) {
        float h = bf2f((u16)(wds[jj >> 1] >> ((jj & 1) * 16)));
        d1 += h * a_l[half * 64 + i * 8 + jj];
        d2 += h * a_l[128 + half * 64 + i * 8 + jj];
      }
    }
    d1 += __shfl_xor(d1, 1);
    d2 += __shfl_xor(d2, 1);
    if (half == 0) {
      s1p[cb * 16384 + row0 + r2] = d1;
      s2p[cb * 16384 + row0 + r2] = d2;
    }
  }
}

// ---------- prep: reduce partials; hybrid shfl/LDS bitonic sort (14 barriers);
// wave-shfl scans (2 barriers); exact denominators folded into c1i/c2i; kn. ----------
__global__ __launch_bounds__(1024) void k_prep(const float* __restrict__ s1p, const float* __restrict__ s2p,
                                               float* __restrict__ e1s, float* __restrict__ e2s,
                                               u32* __restrict__ permM, u32* __restrict__ kng,
                                               float* __restrict__ c1ig, float* __restrict__ c2ig) {
  __shared__ u32 sk[1024];
  __shared__ float s2all[1024];
  __shared__ float s2sv[1024];
  __shared__ float arrA[1024];
  __shared__ float arrB[1024];
  __shared__ float wtA[16], wtB[16];
  const int b = blockIdx.x;
  const int t = threadIdx.x;
  const int lane = t & 63, wid = t >> 6;
  const int id = b * 1024 + t;

  const float s1v = (s1p[id] + s1p[16384 + id] + s1p[32768 + id] + s1p[49152 + id]) * LOG2E;
  const float s2v = (s2p[id] + s2p[16384 + id] + s2p[32768 + id] + s2p[49152 + id]) * LOG2E;
  s2all[t] = s2v;

  u32 key;
  {
    u32 bits = __builtin_bit_cast(u32, s2v);
    u32 k2 = (bits & 0x80000000u) ? ~bits : (bits | 0x80000000u);
    key = (k2 & 0xFFFFFC00u) | (u32)t;   // truncated key | idx
  }

#define SHFL_CE(size_, stride_)                                            \
  {                                                                        \
    u32 partner = (u32)__shfl_xor((int)key, (stride_));                    \
    bool dir = ((t & (size_)) == 0);                                       \
    bool keepMin = (dir == ((t & (stride_)) == 0));                        \
    key = keepMin ? (key < partner ? key : partner)                        \
                  : (key > partner ? key : partner);                       \
  }

#pragma unroll
  for (int size = 2; size <= 64; size <<= 1)
#pragma unroll
    for (int stride = size >> 1; stride > 0; stride >>= 1) SHFL_CE(size, stride);

#pragma unroll 1
  for (int size = 128; size <= 1024; size <<= 1) {
    sk[t] = key;
#pragma unroll 1
    for (int stride = size >> 1; stride >= 64; stride >>= 1) {
      __syncthreads();
      int ixj = t ^ stride;
      if (ixj > t) {
        u32 va = sk[t], vb = sk[ixj];
        bool asc = ((t & size) == 0);
        if ((va > vb) == asc) { sk[t] = vb; sk[ixj] = va; }
      }
    }
    __syncthreads();
    key = sk[t];
#pragma unroll
    for (int stride = 32; stride > 0; stride >>= 1) SHFL_CE(size, stride);
  }
#undef SHFL_CE

  const u32 idx = key & 1023u;
  const float sv = s2all[idx];
  s2sv[t] = sv;
  __syncthreads();

  const float E1 = exp2f(sv), E2 = exp2f(ALPHA * sv);
  e1s[b * 1024 + t] = E1;
  e2s[b * 1024 + t] = E2;
  permM[b * 1024 + t] = idx;

  float aA = E2;
  float aB = exp2f(s2sv[1023 - t]);
#pragma unroll
  for (int off = 1; off < 64; off <<= 1) {
    float uA = __shfl_up(aA, off);
    float uB = __shfl_up(aB, off);
    if (lane >= off) { aA += uA; aB += uB; }
  }
  if (lane == 63) { wtA[wid] = aA; wtB[wid] = aB; }
  __syncthreads();
  {
    float offA = 0.f, offB = 0.f;
#pragma unroll
    for (int i2 = 0; i2 < 16; ++i2) {
      float vA2 = wtA[i2], vB2 = wtB[i2];
      if (i2 < wid) { offA += vA2; offB += vB2; }
    }
    aA += offA;
    aB += offB;
  }
  arrA[t] = aA;
  arrB[t] = aB;
  __syncthreads();

  {
    const float thr = -s1v;
    int lo = 0, hi = 1024;
    while (lo < hi) { int mid = (lo + hi) >> 1; if (s2sv[mid] <= thr) lo = mid + 1; else hi = mid; }
    const int kn = lo;
    float se1suf = (kn == 1024) ? 0.f : arrB[1023 - kn];
    float se2pre = (kn == 0) ? 0.f : arrA[kn - 1];
    const float c1 = exp2f(s1v), c2 = exp2f(ALPHA * s1v);
    const float inv = 1.0f / (c1 * se1suf + c2 * se2pre);
    c1ig[id] = c1 * inv;
    c2ig[id] = c2 * inv;
    kng[id] = (u32)kn;
  }
}

// ---------- sweep2: per (b, 8-f chunk), h accessed via f-major hbt (L1-local).
// Per-element packed scan table Cp[phys(i)][8], phys(i)=i+(i>>5). 4 blocks/CU. ----------
__global__ __launch_bounds__(256, 4) void k_sweep2(const u16* __restrict__ hbt,
                                                   const float* __restrict__ e1s, const float* __restrict__ e2s,
                                                   const u32* __restrict__ permM, const u32* __restrict__ kng,
                                                   const float* __restrict__ c1ig, const float* __restrict__ c2ig,
                                                   const float* __restrict__ betag, float* __restrict__ out) {
  __shared__ u32 Cp[1060][8];      // phys rows: 1024 + 32 pads + sentinel(1056)
  __shared__ float segS1[32][8];
  __shared__ float segP2[32][8];

  const int t = threadIdx.x;
  const int B = blockIdx.x;
  const int b = (B & 7) * 2 + ((B >> 3) & 1);   // XCD swizzle: batch's 64 blocks share an XCD
  const int fc = B >> 4;                         // 0..63 : 8-f chunk

  // f-major h: block touches rows [fc*8, fc*8+8) of hbt = 16 KB, L1-resident
  const u16* hT = hbt + (size_t)b * 512 * 1024 + (size_t)fc * 8 * 1024;

  // phase 1: thread (seg=t>>3, f=t&7) owns sorted positions [seg*32, seg*32+32)
  const int f = t & 7;
  const int seg = t >> 3;          // 0..31
  const int i0 = seg * 32;
  const int p0 = seg * 33;         // phys base: i + (i>>5)
  const u16* hF = hT + (size_t)f * 1024;
  const u32* permB = permM + b * 1024 + i0;
  const float* e1B = e1s + b * 1024 + i0;
  const float* e2B = e2s + b * 1024 + i0;

  // pass A: gather 32 sorted h values (L1-local within 2KB row) + per-seg totals
  u32 hpk[16];
  float ss1 = 0.f, ss2 = 0.f;
#pragma unroll
  for (int c = 0; c < 32; c += 2) {
    u16 h0 = hF[permB[c]];
    u16 h1 = hF[permB[c + 1]];
    hpk[c >> 1] = (u32)h0 | ((u32)h1 << 16);
    ss1 = fmaf(e1B[c], bf2f(h0), ss1);
    ss1 = fmaf(e1B[c + 1], bf2f(h1), ss1);
    ss2 = fmaf(e2B[c], bf2f(h0), ss2);
    ss2 = fmaf(e2B[c + 1], bf2f(h1), ss2);
  }
  segS1[seg][f] = ss1;
  segP2[seg][f] = ss2;
  __syncthreads();

  float sufAfter = 0.f, preBefore = 0.f;
#pragma unroll
  for (int s7 = 0; s7 < 32; ++s7) {
    if (s7 > seg) sufAfter += segS1[s7][f];
    if (s7 < seg) preBefore += segP2[s7][f];
  }

  // pass B: backward walk -> packed bf16 suffix values in 16 regs
  u32 c1p[16];
  {
    float run1 = sufAfter;
#pragma unroll
    for (int c = 31; c >= 0; --c) {
      u16 hv = (u16)(hpk[c >> 1] >> ((c & 1) * 16));
      run1 = fmaf(e1B[c], bf2f(hv), run1);
      if (c & 1) c1p[c >> 1] = (u32)f2bf(run1) << 16;
      else c1p[c >> 1] |= (u32)f2bf(run1);
    }
  }
  // pass C: forward walk -> packed (suffix | excl-prefix) store
  {
    float run2 = preBefore;
#pragma unroll
    for (int c = 0; c < 32; ++c) {
      u16 c1v = (u16)(c1p[c >> 1] >> ((c & 1) * 16));
      Cp[p0 + c][f] = (u32)c1v | ((u32)f2bf(run2) << 16);
      u16 hv = (u16)(hpk[c >> 1] >> ((c & 1) * 16));
      run2 = fmaf(e2B[c], bf2f(hv), run2);
    }
    if (seg == 31) Cp[1056][f] = (u32)f2bf(run2) << 16;   // kn=1024 sentinel
  }
  __syncthreads();

  // phase 2: per row n: one packed lookup + L1-coalesced h + fused elu output
  const float beta = betag[0];
  const int nl = t >> 3;           // 0..31
  const u32* knB = kng + b * 1024;
  const float* c1B = c1ig + b * 1024;
  const float* c2B = c2ig + b * 1024;
#pragma unroll 4
  for (int r = 0; r < 32; ++r) {
    const int n = r * 32 + nl;
    const int kn = (int)knB[n];
    const u32 cp = Cp[kn + (kn >> 5)][f];
    const float A = bf2f((u16)(cp & 0xFFFFu));
    const float Bv = bf2f((u16)(cp >> 16));
    const float hvn = bf2f(hF[n]);
    const float xv = c1B[n] * A + c2B[n] * Bv + beta * hvn;
    out[((size_t)b * 1024 + n) * 512 + fc * 8 + f] = xv > 0.f ? xv : __expf(xv) - 1.0f;
  }
}

extern "C" void kernel_launch(void* const* d_in, const int* in_sizes, int n_in,
                              void* d_out, int out_size, void* d_ws, size_t ws_size,
                              hipStream_t stream) {
  const float* x = (const float*)d_in[0];
  const float* W = (const float*)d_in[1];
  const float* a = (const float*)d_in[2];
  const float* beta = (const float*)d_in[3];
  float* out = (float*)d_out;

  char* ws = (char*)d_ws;
  u16* hbf = (u16*)ws;                                   // [0, 16M)
  u16* hbt = (u16*)(ws + (16u << 20));                   // [16M, 32M) f-major
  char* sm = ws + (32u << 20);
  float* e1s = (float*)(sm);                             // 64 KB each
  float* e2s = (float*)(sm + (64u << 10));
  u32* permM = (u32*)(sm + (128u << 10));
  u32* kng = (u32*)(sm + (192u << 10));
  float* c1i = (float*)(sm + (256u << 10));
  float* c2i = (float*)(sm + (320u << 10));
  float* s1p = (float*)(sm + (512u << 10));              // 256 KB
  float* s2p = (float*)(sm + (768u << 10));              // 256 KB
  u16* wbt = (u16*)(sm + (1024u << 10));                 // 512 KB

  k_cast_wT<<<1024, 256, 0, stream>>>(W, wbt);
  k_gemm1<<<512, 256, 0, stream>>>(x, wbt, a, hbf, hbt, s1p, s2p);
  k_prep<<<16, 1024, 0, stream>>>(s1p, s2p, e1s, e2s, permM, kng, c1i, c2i);
  k_sweep2<<<1024, 256, 0, stream>>>(hbt, e1s, e2s, permM, kng, c1i, c2i, beta, out);
}

// Round 21
// 68.766 us; speedup vs baseline: 1.0334x; 1.0334x over previous
//
#include <hip/hip_runtime.h>

using u16 = unsigned short;
using u32 = unsigned int;
using u64 = unsigned long long;

#define ALPHA 0.2f
#define LOG2E 1.4426950408889634f

typedef __bf16 bf16x8 __attribute__((ext_vector_type(8)));
typedef float f32x4 __attribute__((ext_vector_type(4)));
typedef float f32x16 __attribute__((ext_vector_type(16)));

__device__ __forceinline__ u16 f2bf(float f) {
  u32 u = __builtin_bit_cast(u32, f);
  u += 0x7FFFu + ((u >> 16) & 1u);   // RTNE
  return (u16)(u >> 16);
}
__device__ __forceinline__ float bf2f(u16 h) {
  u32 u = ((u32)h) << 16;
  return __builtin_bit_cast(float, u);
}
__device__ __forceinline__ void gload_lds16(const void* g, void* l) {
  __builtin_amdgcn_global_load_lds((__attribute__((address_space(1))) void*)g,
                                   (__attribute__((address_space(3))) void*)l,
                                   16, 0, 0);
}

// ---------- cast+transpose W: wbt[n][k] = bf16(W[k][n]) ----------
__global__ __launch_bounds__(256) void k_cast_wT(const float* __restrict__ W, u16* __restrict__ wbt) {
  int idx = blockIdx.x * 256 + threadIdx.x;
  int k = idx >> 9, n = idx & 511;
  wbt[n * 512 + k] = f2bf(W[idx]);
}

// ---------- gemm1: h = x@W (M=16384,K=512,N=512). 128x128 tile, 4 waves.
// Triple-buffered, counted vmcnt, XCD-swizzled. Epilogue: hbf + hbt (f-major) + score partials.
__global__ __launch_bounds__(256, 2) void k_gemm1(const float* __restrict__ x, const u16* __restrict__ wbt,
                                                  const float* __restrict__ a,
                                                  u16* __restrict__ hbf, u16* __restrict__ hbt,
                                                  float* __restrict__ s1p, float* __restrict__ s2p) {
  __shared__ __attribute__((aligned(16))) char lds[73728];
  __shared__ __attribute__((aligned(16))) float a_l[256];

  const int t = threadIdx.x;
  const int lane = t & 63;
  const int w = t >> 6;
  const int l31 = lane & 31, lhi = lane >> 5;
  const int rb = w >> 1, cg = w & 1;
  const int g = blockIdx.x;
  const int cb = (g >> 3) & 3;
  const int tile_m = (g & 7) | ((g >> 5) << 3);
  const int row0 = tile_m * 128;
  const int col0 = cb * 128;

  a_l[t] = (t < 128) ? a[col0 + t] : a[512 + col0 + (t - 128)];

  f32x16 acc[2][2];
#pragma unroll
  for (int i = 0; i < 2; ++i)
#pragma unroll
    for (int j = 0; j < 2; ++j)
#pragma unroll
      for (int r = 0; r < 16; ++r) acc[i][j][r] = 0.f;

#define STAGE_G1(kt, Ab, Bb)                                                              \
  {                                                                                       \
    const int k0_ = (kt) * 32;                                                            \
    _Pragma("unroll")                                                                     \
    for (int i = 0; i < 4; ++i) {                                                         \
      int G = i * 256 + t;                                                                \
      int row = G >> 3, ks = G & 7;                                                       \
      gload_lds16(x + (size_t)(row0 + row) * 512 + k0_ + ((ks ^ (row & 7)) * 4),          \
                  (Ab) + (size_t)(i * 256 + w * 64) * 16);                                \
    }                                                                                     \
    _Pragma("unroll")                                                                     \
    for (int i = 0; i < 2; ++i) {                                                         \
      int G = i * 256 + t;                                                                \
      int col = G >> 2, ks = G & 3;                                                       \
      gload_lds16(wbt + (size_t)(col0 + col) * 512 + k0_ + ((ks ^ ((col >> 1) & 3)) * 8), \
                  (Bb) + (size_t)(i * 256 + w * 64) * 16);                                \
    }                                                                                     \
  }

#define COMPUTE_G1(Ab, Bb)                                                                         \
  {                                                                                                \
    _Pragma("unroll")                                                                              \
    for (int ks = 0; ks < 2; ++ks) {                                                               \
      bf16x8 af[2];                                                                                \
      _Pragma("unroll")                                                                            \
      for (int sub = 0; sub < 2; ++sub) {                                                          \
        const int arow = rb * 64 + sub * 32 + l31;                                                 \
        const int kg = ks * 4 + lhi * 2;                                                           \
        f32x4 fa0 = *reinterpret_cast<const f32x4*>((Ab) + (size_t)(arow * 8 + (kg ^ (arow & 7))) * 16); \
        f32x4 fa1 = *reinterpret_cast<const f32x4*>((Ab) + (size_t)(arow * 8 + ((kg + 1) ^ (arow & 7))) * 16); \
        _Pragma("unroll")                                                                          \
        for (int jj = 0; jj < 4; ++jj) {                                                           \
          af[sub][jj] = (__bf16)fa0[jj];                                                           \
          af[sub][jj + 4] = (__bf16)fa1[jj];                                                       \
        }                                                                                          \
      }                                                                                            \
      bf16x8 bfr[2];                                                                               \
      _Pragma("unroll")                                                                            \
      for (int bt = 0; bt < 2; ++bt) {                                                             \
        const int bcol = cg * 64 + bt * 32 + l31;                                                  \
        const int kslot = (ks * 2 + lhi) ^ ((bcol >> 1) & 3);                                      \
        bfr[bt] = *reinterpret_cast<const bf16x8*>((Bb) + (size_t)(bcol * 4 + kslot) * 16);        \
      }                                                                                            \
      _Pragma("unroll")                                                                            \
      for (int sub = 0; sub < 2; ++sub)                                                            \
        _Pragma("unroll")                                                                          \
        for (int bt = 0; bt < 2; ++bt)                                                             \
          acc[sub][bt] = __builtin_amdgcn_mfma_f32_32x32x16_bf16(af[sub], bfr[bt], acc[sub][bt], 0, 0, 0); \
    }                                                                                              \
  }

  char* Ac = lds;             char* Bc = lds + 49152;
  char* An = lds + 16384;     char* Bn = lds + 57344;
  char* As = lds + 32768;     char* Bs = lds + 65536;

  STAGE_G1(0, Ac, Bc);
  STAGE_G1(1, An, Bn);
  __builtin_amdgcn_sched_barrier(0);
  asm volatile("s_waitcnt vmcnt(6) lgkmcnt(0)" ::: "memory");
  __builtin_amdgcn_s_barrier();
  __builtin_amdgcn_sched_barrier(0);

#pragma unroll 1
  for (int kt = 0; kt < 14; ++kt) {
    STAGE_G1(kt + 2, As, Bs);
    COMPUTE_G1(Ac, Bc);
    __builtin_amdgcn_sched_barrier(0);
    asm volatile("s_waitcnt vmcnt(6)" ::: "memory");
    __builtin_amdgcn_s_barrier();
    __builtin_amdgcn_sched_barrier(0);
    char* ta = Ac; Ac = An; An = As; As = ta;
    char* tb = Bc; Bc = Bn; Bn = Bs; Bs = tb;
  }
  COMPUTE_G1(Ac, Bc);
  __builtin_amdgcn_sched_barrier(0);
  asm volatile("s_waitcnt vmcnt(0)" ::: "memory");
  __builtin_amdgcn_s_barrier();
  __builtin_amdgcn_sched_barrier(0);
  COMPUTE_G1(An, Bn);
#undef STAGE_G1
#undef COMPUTE_G1

  __syncthreads();

  u16* lT = (u16*)lds;
#pragma unroll
  for (int sub = 0; sub < 2; ++sub)
#pragma unroll
    for (int bt = 0; bt < 2; ++bt) {
      const int col = cg * 64 + bt * 32 + l31;
#pragma unroll
      for (int r = 0; r < 16; ++r) {
        int row = rb * 64 + sub * 32 + (r & 3) + 8 * (r >> 2) + 4 * lhi;
        lT[row * 136 + col] = f2bf(acc[sub][bt][r]);
      }
    }
  __syncthreads();

  // hbf: [row][col] coalesced (2048 granules)
#pragma unroll
  for (int i = 0; i < 8; ++i) {
    int G = i * 256 + t;
    int row = G >> 4, gg = G & 15;
    uint4 v = *reinterpret_cast<const uint4*>(&lT[row * 136 + gg * 8]);
    *reinterpret_cast<uint4*>(&hbf[(size_t)(row0 + row) * 512 + col0 + gg * 8]) = v;
  }
  // hbt: [b][f][m] (f-major, staging source for sweep2)
  const int bb = row0 >> 10;
  const int nb = row0 & 1023;
#pragma unroll
  for (int i = 0; i < 8; ++i) {
    int G = i * 256 + t;
    int col = G & 127, rg = G >> 7;
    u32 wd[4];
#pragma unroll
    for (int jj = 0; jj < 4; ++jj) {
      u16 lo = lT[(rg * 8 + 2 * jj) * 136 + col];
      u16 hi = lT[(rg * 8 + 2 * jj + 1) * 136 + col];
      wd[jj] = (u32)lo | ((u32)hi << 16);
    }
    uint4 o = {wd[0], wd[1], wd[2], wd[3]};
    *reinterpret_cast<uint4*>(&hbt[(size_t)(bb * 512 + col0 + col) * 1024 + nb + rg * 8]) = o;
  }
  // score partials
  {
    const int r2 = t >> 1, half = t & 1;
    float d1 = 0.f, d2 = 0.f;
#pragma unroll
    for (int i = 0; i < 8; ++i) {
      uint4 v = *reinterpret_cast<const uint4*>(&lT[r2 * 136 + half * 64 + i * 8]);
      u32 wds[4] = {v.x, v.y, v.z, v.w};
#pragma unroll
      for (int jj = 0; jj < 8; ++jj) {
        float h = bf2f((u16)(wds[jj >> 1] >> ((jj & 1) * 16)));
        d1 += h * a_l[half * 64 + i * 8 + jj];
        d2 += h * a_l[128 + half * 64 + i * 8 + jj];
      }
    }
    d1 += __shfl_xor(d1, 1);
    d2 += __shfl_xor(d2, 1);
    if (half == 0) {
      s1p[cb * 16384 + row0 + r2] = d1;
      s2p[cb * 16384 + row0 + r2] = d2;
    }
  }
}

// ---------- prep: reduce partials; hybrid shfl/LDS bitonic sort (14 barriers);
// wave-shfl scans (2 barriers); exact denominators folded into c1i/c2i; kn. ----------
__global__ __launch_bounds__(1024) void k_prep(const float* __restrict__ s1p, const float* __restrict__ s2p,
                                               float* __restrict__ e1s, float* __restrict__ e2s,
                                               u32* __restrict__ permM, u32* __restrict__ kng,
                                               float* __restrict__ c1ig, float* __restrict__ c2ig) {
  __shared__ u32 sk[1024];
  __shared__ float s2all[1024];
  __shared__ float s2sv[1024];
  __shared__ float arrA[1024];
  __shared__ float arrB[1024];
  __shared__ float wtA[16], wtB[16];
  const int b = blockIdx.x;
  const int t = threadIdx.x;
  const int lane = t & 63, wid = t >> 6;
  const int id = b * 1024 + t;

  const float s1v = (s1p[id] + s1p[16384 + id] + s1p[32768 + id] + s1p[49152 + id]) * LOG2E;
  const float s2v = (s2p[id] + s2p[16384 + id] + s2p[32768 + id] + s2p[49152 + id]) * LOG2E;
  s2all[t] = s2v;

  u32 key;
  {
    u32 bits = __builtin_bit_cast(u32, s2v);
    u32 k2 = (bits & 0x80000000u) ? ~bits : (bits | 0x80000000u);
    key = (k2 & 0xFFFFFC00u) | (u32)t;   // truncated key | idx
  }

#define SHFL_CE(size_, stride_)                                            \
  {                                                                        \
    u32 partner = (u32)__shfl_xor((int)key, (stride_));                    \
    bool dir = ((t & (size_)) == 0);                                       \
    bool keepMin = (dir == ((t & (stride_)) == 0));                        \
    key = keepMin ? (key < partner ? key : partner)                        \
                  : (key > partner ? key : partner);                       \
  }

#pragma unroll
  for (int size = 2; size <= 64; size <<= 1)
#pragma unroll
    for (int stride = size >> 1; stride > 0; stride >>= 1) SHFL_CE(size, stride);

#pragma unroll 1
  for (int size = 128; size <= 1024; size <<= 1) {
    sk[t] = key;
#pragma unroll 1
    for (int stride = size >> 1; stride >= 64; stride >>= 1) {
      __syncthreads();
      int ixj = t ^ stride;
      if (ixj > t) {
        u32 va = sk[t], vb = sk[ixj];
        bool asc = ((t & size) == 0);
        if ((va > vb) == asc) { sk[t] = vb; sk[ixj] = va; }
      }
    }
    __syncthreads();
    key = sk[t];
#pragma unroll
    for (int stride = 32; stride > 0; stride >>= 1) SHFL_CE(size, stride);
  }
#undef SHFL_CE

  const u32 idx = key & 1023u;
  const float sv = s2all[idx];
  s2sv[t] = sv;
  __syncthreads();

  const float E1 = exp2f(sv), E2 = exp2f(ALPHA * sv);
  e1s[b * 1024 + t] = E1;
  e2s[b * 1024 + t] = E2;
  permM[b * 1024 + t] = idx;

  float aA = E2;
  float aB = exp2f(s2sv[1023 - t]);
#pragma unroll
  for (int off = 1; off < 64; off <<= 1) {
    float uA = __shfl_up(aA, off);
    float uB = __shfl_up(aB, off);
    if (lane >= off) { aA += uA; aB += uB; }
  }
  if (lane == 63) { wtA[wid] = aA; wtB[wid] = aB; }
  __syncthreads();
  {
    float offA = 0.f, offB = 0.f;
#pragma unroll
    for (int i2 = 0; i2 < 16; ++i2) {
      float vA2 = wtA[i2], vB2 = wtB[i2];
      if (i2 < wid) { offA += vA2; offB += vB2; }
    }
    aA += offA;
    aB += offB;
  }
  arrA[t] = aA;
  arrB[t] = aB;
  __syncthreads();

  {
    const float thr = -s1v;
    int lo = 0, hi = 1024;
    while (lo < hi) { int mid = (lo + hi) >> 1; if (s2sv[mid] <= thr) lo = mid + 1; else hi = mid; }
    const int kn = lo;
    float se1suf = (kn == 1024) ? 0.f : arrB[1023 - kn];
    float se2pre = (kn == 0) ? 0.f : arrA[kn - 1];
    const float c1 = exp2f(s1v), c2 = exp2f(ALPHA * s1v);
    const float inv = 1.0f / (c1 * se1suf + c2 * se2pre);
    c1ig[id] = c1 * inv;
    c2ig[id] = c2 * inv;
    kng[id] = (u32)kn;
  }
}

// ---------- sweep2: per (b, 8-f chunk). Stage 16KB h-chunk from hbt (contiguous,
// coalesced) into LDS h_s[8][1040]; gathers + phase-2 reads hit LDS. 3 blocks/CU. ----------
__global__ __launch_bounds__(256, 3) void k_sweep2(const u16* __restrict__ hbt,
                                                   const float* __restrict__ e1s, const float* __restrict__ e2s,
                                                   const u32* __restrict__ permM, const u32* __restrict__ kng,
                                                   const float* __restrict__ c1ig, const float* __restrict__ c2ig,
                                                   const float* __restrict__ betag, float* __restrict__ out) {
  __shared__ __attribute__((aligned(16))) u16 h_s[8 * 1040];   // row stride 1040 (bank shift 8f)
  __shared__ u32 Cp[1060][8];      // phys rows: 1024 + 32 pads + sentinel(1056)
  __shared__ float segS1[32][8];
  __shared__ float segP2[32][8];

  const int t = threadIdx.x;
  const int B = blockIdx.x;
  const int b = (B & 7) * 2 + ((B >> 3) & 1);   // XCD swizzle: batch's 64 blocks share an XCD
  const int fc = B >> 4;                         // 0..63 : 8-f chunk

  // stage: 8 contiguous f-rows (16 KB) from hbt, fully coalesced
  const u16* hT = hbt + (size_t)b * 512 * 1024 + (size_t)fc * 8 * 1024;
#pragma unroll
  for (int i = 0; i < 4; ++i) {
    int G = i * 256 + t;                 // 0..1023 granules of 8 u16
    int fr = G >> 7, gg = G & 127;
    uint4 v = *reinterpret_cast<const uint4*>(hT + (size_t)G * 8);
    *reinterpret_cast<uint4*>(&h_s[fr * 1040 + gg * 8]) = v;
  }
  __syncthreads();

  // phase 1: thread (seg=t>>3, f=t&7) owns sorted positions [seg*32, seg*32+32)
  const int f = t & 7;
  const int seg = t >> 3;          // 0..31
  const int i0 = seg * 32;
  const int p0 = seg * 33;         // phys base: i + (i>>5)
  const u16* hF = h_s + f * 1040;
  const u32* permB = permM + b * 1024 + i0;
  const float* e1B = e1s + b * 1024 + i0;
  const float* e2B = e2s + b * 1024 + i0;

  // pass A: gather 32 sorted h values from LDS + per-seg totals
  u32 hpk[16];
  float ss1 = 0.f, ss2 = 0.f;
#pragma unroll
  for (int c = 0; c < 32; c += 2) {
    u16 h0 = hF[permB[c]];
    u16 h1 = hF[permB[c + 1]];
    hpk[c >> 1] = (u32)h0 | ((u32)h1 << 16);
    ss1 = fmaf(e1B[c], bf2f(h0), ss1);
    ss1 = fmaf(e1B[c + 1], bf2f(h1), ss1);
    ss2 = fmaf(e2B[c], bf2f(h0), ss2);
    ss2 = fmaf(e2B[c + 1], bf2f(h1), ss2);
  }
  segS1[seg][f] = ss1;
  segP2[seg][f] = ss2;
  __syncthreads();

  float sufAfter = 0.f, preBefore = 0.f;
#pragma unroll
  for (int s7 = 0; s7 < 32; ++s7) {
    if (s7 > seg) sufAfter += segS1[s7][f];
    if (s7 < seg) preBefore += segP2[s7][f];
  }

  // pass B: backward walk -> packed bf16 suffix values in 16 regs
  u32 c1p[16];
  {
    float run1 = sufAfter;
#pragma unroll
    for (int c = 31; c >= 0; --c) {
      u16 hv = (u16)(hpk[c >> 1] >> ((c & 1) * 16));
      run1 = fmaf(e1B[c], bf2f(hv), run1);
      if (c & 1) c1p[c >> 1] = (u32)f2bf(run1) << 16;
      else c1p[c >> 1] |= (u32)f2bf(run1);
    }
  }
  // pass C: forward walk -> packed (suffix | excl-prefix) store
  {
    float run2 = preBefore;
#pragma unroll
    for (int c = 0; c < 32; ++c) {
      u16 c1v = (u16)(c1p[c >> 1] >> ((c & 1) * 16));
      Cp[p0 + c][f] = (u32)c1v | ((u32)f2bf(run2) << 16);
      u16 hv = (u16)(hpk[c >> 1] >> ((c & 1) * 16));
      run2 = fmaf(e2B[c], bf2f(hv), run2);
    }
    if (seg == 31) Cp[1056][f] = (u32)f2bf(run2) << 16;   // kn=1024 sentinel
  }
  __syncthreads();

  // phase 2: per row n: one packed lookup + LDS h + fused elu output
  const float beta = betag[0];
  const int nl = t >> 3;           // 0..31
  const u32* knB = kng + b * 1024;
  const float* c1B = c1ig + b * 1024;
  const float* c2B = c2ig + b * 1024;
#pragma unroll 4
  for (int r = 0; r < 32; ++r) {
    const int n = r * 32 + nl;
    const int kn = (int)knB[n];
    const u32 cp = Cp[kn + (kn >> 5)][f];
    const float A = bf2f((u16)(cp & 0xFFFFu));
    const float Bv = bf2f((u16)(cp >> 16));
    const float hvn = bf2f(hF[n]);
    const float xv = c1B[n] * A + c2B[n] * Bv + beta * hvn;
    out[((size_t)b * 1024 + n) * 512 + fc * 8 + f] = xv > 0.f ? xv : __expf(xv) - 1.0f;
  }
}

extern "C" void kernel_launch(void* const* d_in, const int* in_sizes, int n_in,
                              void* d_out, int out_size, void* d_ws, size_t ws_size,
                              hipStream_t stream) {
  const float* x = (const float*)d_in[0];
  const float* W = (const float*)d_in[1];
  const float* a = (const float*)d_in[2];
  const float* beta = (const float*)d_in[3];
  float* out = (float*)d_out;

  char* ws = (char*)d_ws;
  u16* hbf = (u16*)ws;                                   // [0, 16M)
  u16* hbt = (u16*)(ws + (16u << 20));                   // [16M, 32M) f-major
  char* sm = ws + (32u << 20);
  float* e1s = (float*)(sm);                             // 64 KB each
  float* e2s = (float*)(sm + (64u << 10));
  u32* permM = (u32*)(sm + (128u << 10));
  u32* kng = (u32*)(sm + (192u << 10));
  float* c1i = (float*)(sm + (256u << 10));
  float* c2i = (float*)(sm + (320u << 10));
  float* s1p = (float*)(sm + (512u << 10));              // 256 KB
  float* s2p = (float*)(sm + (768u << 10));              // 256 KB
  u16* wbt = (u16*)(sm + (1024u << 10));                 // 512 KB

  k_cast_wT<<<1024, 256, 0, stream>>>(W, wbt);
  k_gemm1<<<512, 256, 0, stream>>>(x, wbt, a, hbf, hbt, s1p, s2p);
  k_prep<<<16, 1024, 0, stream>>>(s1p, s2p, e1s, e2s, permM, kng, c1i, c2i);
  k_sweep2<<<1024, 256, 0, stream>>>(hbt, e1s, e2s, permM, kng, c1i, c2i, beta, out);
}

// Round 22
// 60.587 us; speedup vs baseline: 1.1729x; 1.1350x over previous
//
#include <hip/hip_runtime.h>

using u16 = unsigned short;
using u32 = unsigned int;
using u64 = unsigned long long;

#define ALPHA 0.2f
#define LOG2E 1.4426950408889634f

typedef __bf16 bf16x8 __attribute__((ext_vector_type(8)));
typedef float f32x4 __attribute__((ext_vector_type(4)));
typedef float f32x16 __attribute__((ext_vector_type(16)));

__device__ __forceinline__ u16 f2bf(float f) {
  u32 u = __builtin_bit_cast(u32, f);
  u += 0x7FFFu + ((u >> 16) & 1u);   // RTNE
  return (u16)(u >> 16);
}
__device__ __forceinline__ float bf2f(u16 h) {
  u32 u = ((u32)h) << 16;
  return __builtin_bit_cast(float, u);
}
__device__ __forceinline__ void gload_lds16(const void* g, void* l) {
  __builtin_amdgcn_global_load_lds((__attribute__((address_space(1))) void*)g,
                                   (__attribute__((address_space(3))) void*)l,
                                   16, 0, 0);
}

// ---------- cast+transpose W: wbt[n][k] = bf16(W[k][n]) ----------
__global__ __launch_bounds__(256) void k_cast_wT(const float* __restrict__ W, u16* __restrict__ wbt) {
  int idx = blockIdx.x * 256 + threadIdx.x;
  int k = idx >> 9, n = idx & 511;
  wbt[n * 512 + k] = f2bf(W[idx]);
}

// ---------- gemm1: h = x@W (M=16384,K=512,N=512). 128x128 tile, 4 waves.
// Triple-buffered, counted vmcnt, XCD-swizzled. Epilogue: hbf + score partials.
__global__ __launch_bounds__(256, 2) void k_gemm1(const float* __restrict__ x, const u16* __restrict__ wbt,
                                                  const float* __restrict__ a,
                                                  u16* __restrict__ hbf,
                                                  float* __restrict__ s1p, float* __restrict__ s2p) {
  __shared__ __attribute__((aligned(16))) char lds[73728];
  __shared__ __attribute__((aligned(16))) float a_l[256];

  const int t = threadIdx.x;
  const int lane = t & 63;
  const int w = t >> 6;
  const int l31 = lane & 31, lhi = lane >> 5;
  const int rb = w >> 1, cg = w & 1;
  const int g = blockIdx.x;
  const int cb = (g >> 3) & 3;
  const int tile_m = (g & 7) | ((g >> 5) << 3);
  const int row0 = tile_m * 128;
  const int col0 = cb * 128;

  a_l[t] = (t < 128) ? a[col0 + t] : a[512 + col0 + (t - 128)];

  f32x16 acc[2][2];
#pragma unroll
  for (int i = 0; i < 2; ++i)
#pragma unroll
    for (int j = 0; j < 2; ++j)
#pragma unroll
      for (int r = 0; r < 16; ++r) acc[i][j][r] = 0.f;

#define STAGE_G1(kt, Ab, Bb)                                                              \
  {                                                                                       \
    const int k0_ = (kt) * 32;                                                            \
    _Pragma("unroll")                                                                     \
    for (int i = 0; i < 4; ++i) {                                                         \
      int G = i * 256 + t;                                                                \
      int row = G >> 3, ks = G & 7;                                                       \
      gload_lds16(x + (size_t)(row0 + row) * 512 + k0_ + ((ks ^ (row & 7)) * 4),          \
                  (Ab) + (size_t)(i * 256 + w * 64) * 16);                                \
    }                                                                                     \
    _Pragma("unroll")                                                                     \
    for (int i = 0; i < 2; ++i) {                                                         \
      int G = i * 256 + t;                                                                \
      int col = G >> 2, ks = G & 3;                                                       \
      gload_lds16(wbt + (size_t)(col0 + col) * 512 + k0_ + ((ks ^ ((col >> 1) & 3)) * 8), \
                  (Bb) + (size_t)(i * 256 + w * 64) * 16);                                \
    }                                                                                     \
  }

#define COMPUTE_G1(Ab, Bb)                                                                         \
  {                                                                                                \
    _Pragma("unroll")                                                                              \
    for (int ks = 0; ks < 2; ++ks) {                                                               \
      bf16x8 af[2];                                                                                \
      _Pragma("unroll")                                                                            \
      for (int sub = 0; sub < 2; ++sub) {                                                          \
        const int arow = rb * 64 + sub * 32 + l31;                                                 \
        const int kg = ks * 4 + lhi * 2;                                                           \
        f32x4 fa0 = *reinterpret_cast<const f32x4*>((Ab) + (size_t)(arow * 8 + (kg ^ (arow & 7))) * 16); \
        f32x4 fa1 = *reinterpret_cast<const f32x4*>((Ab) + (size_t)(arow * 8 + ((kg + 1) ^ (arow & 7))) * 16); \
        _Pragma("unroll")                                                                          \
        for (int jj = 0; jj < 4; ++jj) {                                                           \
          af[sub][jj] = (__bf16)fa0[jj];                                                           \
          af[sub][jj + 4] = (__bf16)fa1[jj];                                                       \
        }                                                                                          \
      }                                                                                            \
      bf16x8 bfr[2];                                                                               \
      _Pragma("unroll")                                                                            \
      for (int bt = 0; bt < 2; ++bt) {                                                             \
        const int bcol = cg * 64 + bt * 32 + l31;                                                  \
        const int kslot = (ks * 2 + lhi) ^ ((bcol >> 1) & 3);                                      \
        bfr[bt] = *reinterpret_cast<const bf16x8*>((Bb) + (size_t)(bcol * 4 + kslot) * 16);        \
      }                                                                                            \
      _Pragma("unroll")                                                                            \
      for (int sub = 0; sub < 2; ++sub)                                                            \
        _Pragma("unroll")                                                                          \
        for (int bt = 0; bt < 2; ++bt)                                                             \
          acc[sub][bt] = __builtin_amdgcn_mfma_f32_32x32x16_bf16(af[sub], bfr[bt], acc[sub][bt], 0, 0, 0); \
    }                                                                                              \
  }

  char* Ac = lds;             char* Bc = lds + 49152;
  char* An = lds + 16384;     char* Bn = lds + 57344;
  char* As = lds + 32768;     char* Bs = lds + 65536;

  STAGE_G1(0, Ac, Bc);
  STAGE_G1(1, An, Bn);
  __builtin_amdgcn_sched_barrier(0);
  asm volatile("s_waitcnt vmcnt(6) lgkmcnt(0)" ::: "memory");
  __builtin_amdgcn_s_barrier();
  __builtin_amdgcn_sched_barrier(0);

#pragma unroll 1
  for (int kt = 0; kt < 14; ++kt) {
    STAGE_G1(kt + 2, As, Bs);
    COMPUTE_G1(Ac, Bc);
    __builtin_amdgcn_sched_barrier(0);
    asm volatile("s_waitcnt vmcnt(6)" ::: "memory");
    __builtin_amdgcn_s_barrier();
    __builtin_amdgcn_sched_barrier(0);
    char* ta = Ac; Ac = An; An = As; As = ta;
    char* tb = Bc; Bc = Bn; Bn = Bs; Bs = tb;
  }
  COMPUTE_G1(Ac, Bc);
  __builtin_amdgcn_sched_barrier(0);
  asm volatile("s_waitcnt vmcnt(0)" ::: "memory");
  __builtin_amdgcn_s_barrier();
  __builtin_amdgcn_sched_barrier(0);
  COMPUTE_G1(An, Bn);
#undef STAGE_G1
#undef COMPUTE_G1

  __syncthreads();

  u16* lT = (u16*)lds;
#pragma unroll
  for (int sub = 0; sub < 2; ++sub)
#pragma unroll
    for (int bt = 0; bt < 2; ++bt) {
      const int col = cg * 64 + bt * 32 + l31;
#pragma unroll
      for (int r = 0; r < 16; ++r) {
        int row = rb * 64 + sub * 32 + (r & 3) + 8 * (r >> 2) + 4 * lhi;
        lT[row * 136 + col] = f2bf(acc[sub][bt][r]);
      }
    }
  __syncthreads();

#pragma unroll
  for (int i = 0; i < 8; ++i) {
    int G = i * 256 + t;
    int row = G >> 4, gg = G & 15;
    uint4 v = *reinterpret_cast<const uint4*>(&lT[row * 136 + gg * 8]);
    *reinterpret_cast<uint4*>(&hbf[(size_t)(row0 + row) * 512 + col0 + gg * 8]) = v;
  }
  {
    const int r2 = t >> 1, half = t & 1;
    float d1 = 0.f, d2 = 0.f;
#pragma unroll
    for (int i = 0; i < 8; ++i) {
      uint4 v = *reinterpret_cast<const uint4*>(&lT[r2 * 136 + half * 64 + i * 8]);
      u32 wds[4] = {v.x, v.y, v.z, v.w};
#pragma unroll
      for (int jj = 0; jj < 8; ++jj) {
        float h = bf2f((u16)(wds[jj >> 1] >> ((jj & 1) * 16)));
        d1 += h * a_l[half * 64 + i * 8 + jj];
        d2 += h * a_l[128 + half * 64 + i * 8 + jj];
      }
    }
    d1 += __shfl_xor(d1, 1);
    d2 += __shfl_xor(d2, 1);
    if (half == 0) {
      s1p[cb * 16384 + row0 + r2] = d1;
      s2p[cb * 16384 + row0 + r2] = d2;
    }
  }
}

// ---------- prep: reduce partials; hybrid shfl/LDS bitonic sort (14 barriers);
// wave-shfl scans (2 barriers); exact denominators folded into c1i/c2i; kn. ----------
__global__ __launch_bounds__(1024) void k_prep(const float* __restrict__ s1p, const float* __restrict__ s2p,
                                               float* __restrict__ e1s, float* __restrict__ e2s,
                                               u32* __restrict__ permM, u32* __restrict__ kng,
                                               float* __restrict__ c1ig, float* __restrict__ c2ig) {
  __shared__ u32 sk[1024];
  __shared__ float s2all[1024];
  __shared__ float s2sv[1024];
  __shared__ float arrA[1024];
  __shared__ float arrB[1024];
  __shared__ float wtA[16], wtB[16];
  const int b = blockIdx.x;
  const int t = threadIdx.x;
  const int lane = t & 63, wid = t >> 6;
  const int id = b * 1024 + t;

  const float s1v = (s1p[id] + s1p[16384 + id] + s1p[32768 + id] + s1p[49152 + id]) * LOG2E;
  const float s2v = (s2p[id] + s2p[16384 + id] + s2p[32768 + id] + s2p[49152 + id]) * LOG2E;
  s2all[t] = s2v;

  u32 key;
  {
    u32 bits = __builtin_bit_cast(u32, s2v);
    u32 k2 = (bits & 0x80000000u) ? ~bits : (bits | 0x80000000u);
    key = (k2 & 0xFFFFFC00u) | (u32)t;   // truncated key | idx
  }

#define SHFL_CE(size_, stride_)                                            \
  {                                                                        \
    u32 partner = (u32)__shfl_xor((int)key, (stride_));                    \
    bool dir = ((t & (size_)) == 0);                                       \
    bool keepMin = (dir == ((t & (stride_)) == 0));                        \
    key = keepMin ? (key < partner ? key : partner)                        \
                  : (key > partner ? key : partner);                       \
  }

#pragma unroll
  for (int size = 2; size <= 64; size <<= 1)
#pragma unroll
    for (int stride = size >> 1; stride > 0; stride >>= 1) SHFL_CE(size, stride);

#pragma unroll 1
  for (int size = 128; size <= 1024; size <<= 1) {
    sk[t] = key;
#pragma unroll 1
    for (int stride = size >> 1; stride >= 64; stride >>= 1) {
      __syncthreads();
      int ixj = t ^ stride;
      if (ixj > t) {
        u32 va = sk[t], vb = sk[ixj];
        bool asc = ((t & size) == 0);
        if ((va > vb) == asc) { sk[t] = vb; sk[ixj] = va; }
      }
    }
    __syncthreads();
    key = sk[t];
#pragma unroll
    for (int stride = 32; stride > 0; stride >>= 1) SHFL_CE(size, stride);
  }
#undef SHFL_CE

  const u32 idx = key & 1023u;
  const float sv = s2all[idx];
  s2sv[t] = sv;
  __syncthreads();

  const float E1 = exp2f(sv), E2 = exp2f(ALPHA * sv);
  e1s[b * 1024 + t] = E1;
  e2s[b * 1024 + t] = E2;
  permM[b * 1024 + t] = idx;

  float aA = E2;
  float aB = exp2f(s2sv[1023 - t]);
#pragma unroll
  for (int off = 1; off < 64; off <<= 1) {
    float uA = __shfl_up(aA, off);
    float uB = __shfl_up(aB, off);
    if (lane >= off) { aA += uA; aB += uB; }
  }
  if (lane == 63) { wtA[wid] = aA; wtB[wid] = aB; }
  __syncthreads();
  {
    float offA = 0.f, offB = 0.f;
#pragma unroll
    for (int i2 = 0; i2 < 16; ++i2) {
      float vA2 = wtA[i2], vB2 = wtB[i2];
      if (i2 < wid) { offA += vA2; offB += vB2; }
    }
    aA += offA;
    aB += offB;
  }
  arrA[t] = aA;
  arrB[t] = aB;
  __syncthreads();

  {
    const float thr = -s1v;
    int lo = 0, hi = 1024;
    while (lo < hi) { int mid = (lo + hi) >> 1; if (s2sv[mid] <= thr) lo = mid + 1; else hi = mid; }
    const int kn = lo;
    float se1suf = (kn == 1024) ? 0.f : arrB[1023 - kn];
    float se2pre = (kn == 0) ? 0.f : arrA[kn - 1];
    const float c1 = exp2f(s1v), c2 = exp2f(ALPHA * s1v);
    const float inv = 1.0f / (c1 * se1suf + c2 * se2pre);
    c1ig[id] = c1 * inv;
    c2ig[id] = c2 * inv;
    kng[id] = (u32)kn;
  }
}

// ---------- sweep2: per (b, 8-f chunk), 256 thr = 32 segs x 8 f. Per-element
// packed scan table Cp[phys(i)][8], phys(i)=i+(i>>5). ~38KB LDS -> 4 blocks/CU.
// kn cached in LDS (u16); c1i/c2i broadcast from global. ----------
__global__ __launch_bounds__(256, 4) void k_sweep2(const u16* __restrict__ hbf,
                                                   const float* __restrict__ e1s, const float* __restrict__ e2s,
                                                   const u32* __restrict__ permM, const u32* __restrict__ kng,
                                                   const float* __restrict__ c1ig, const float* __restrict__ c2ig,
                                                   const float* __restrict__ betag, float* __restrict__ out) {
  __shared__ u32 Cp[1060][8];      // phys rows: 1024 + 32 pads + sentinel(1056)
  __shared__ u16 kn_l[1024];
  __shared__ float segS1[32][8];
  __shared__ float segP2[32][8];

  const int t = threadIdx.x;
  const int B = blockIdx.x;
  const int b = (B & 7) * 2 + ((B >> 3) & 1);   // XCD swizzle: batch's 64 blocks share an XCD
  const int fc = B >> 4;                         // 0..63 : 8-f chunk

  const u16* hB = hbf + (size_t)b * 1024 * 512 + fc * 8;

#pragma unroll
  for (int q = 0; q < 4; ++q) {
    int i = q * 256 + t;
    kn_l[i] = (u16)kng[b * 1024 + i];
  }

  // phase 1: thread (seg=t>>3, f=t&7) owns sorted positions [seg*32, seg*32+32)
  const int f = t & 7;
  const int seg = t >> 3;          // 0..31
  const int i0 = seg * 32;
  const int p0 = seg * 33;         // phys base: i + (i>>5)
  const u32* permB = permM + b * 1024 + i0;
  const float* e1B = e1s + b * 1024 + i0;
  const float* e2B = e2s + b * 1024 + i0;

  // pass A: gather 32 sorted h values (packed pairs) + per-seg totals
  u32 hpk[16];
  float ss1 = 0.f, ss2 = 0.f;
#pragma unroll
  for (int c = 0; c < 32; c += 2) {
    u16 h0 = hB[(size_t)permB[c] * 512 + f];
    u16 h1 = hB[(size_t)permB[c + 1] * 512 + f];
    hpk[c >> 1] = (u32)h0 | ((u32)h1 << 16);
    ss1 = fmaf(e1B[c], bf2f(h0), ss1);
    ss1 = fmaf(e1B[c + 1], bf2f(h1), ss1);
    ss2 = fmaf(e2B[c], bf2f(h0), ss2);
    ss2 = fmaf(e2B[c + 1], bf2f(h1), ss2);
  }
  segS1[seg][f] = ss1;
  segP2[seg][f] = ss2;
  __syncthreads();

  float sufAfter = 0.f, preBefore = 0.f;
#pragma unroll
  for (int s7 = 0; s7 < 32; ++s7) {
    if (s7 > seg) sufAfter += segS1[s7][f];
    if (s7 < seg) preBefore += segP2[s7][f];
  }

  // pass B: backward walk -> packed bf16 suffix values in 16 regs
  u32 c1p[16];
  {
    float run1 = sufAfter;
#pragma unroll
    for (int c = 31; c >= 0; --c) {
      u16 hv = (u16)(hpk[c >> 1] >> ((c & 1) * 16));
      run1 = fmaf(e1B[c], bf2f(hv), run1);
      if (c & 1) c1p[c >> 1] = (u32)f2bf(run1) << 16;
      else c1p[c >> 1] |= (u32)f2bf(run1);
    }
  }
  // pass C: forward walk -> packed (suffix | excl-prefix) store
  {
    float run2 = preBefore;
#pragma unroll
    for (int c = 0; c < 32; ++c) {
      u16 c1v = (u16)(c1p[c >> 1] >> ((c & 1) * 16));
      Cp[p0 + c][f] = (u32)c1v | ((u32)f2bf(run2) << 16);
      u16 hv = (u16)(hpk[c >> 1] >> ((c & 1) * 16));
      run2 = fmaf(e2B[c], bf2f(hv), run2);
    }
    if (seg == 31) Cp[1056][f] = (u32)f2bf(run2) << 16;   // kn=1024 sentinel
  }
  __syncthreads();

  // phase 2: per row n: one packed lookup + fused elu output (32 rows/iter, 32 iters)
  const float beta = betag[0];
  const int nl = t >> 3;           // 0..31
  const float* c1B = c1ig + b * 1024;
  const float* c2B = c2ig + b * 1024;
#pragma unroll 4
  for (int r = 0; r < 32; ++r) {
    const int n = r * 32 + nl;
    const int kn = (int)kn_l[n];
    const u32 cp = Cp[kn + (kn >> 5)][f];
    const float A = bf2f((u16)(cp & 0xFFFFu));
    const float Bv = bf2f((u16)(cp >> 16));
    const float hvn = bf2f(hB[(size_t)n * 512 + f]);
    const float xv = c1B[n] * A + c2B[n] * Bv + beta * hvn;
    out[((size_t)b * 1024 + n) * 512 + fc * 8 + f] = xv > 0.f ? xv : __expf(xv) - 1.0f;
  }
}

extern "C" void kernel_launch(void* const* d_in, const int* in_sizes, int n_in,
                              void* d_out, int out_size, void* d_ws, size_t ws_size,
                              hipStream_t stream) {
  const float* x = (const float*)d_in[0];
  const float* W = (const float*)d_in[1];
  const float* a = (const float*)d_in[2];
  const float* beta = (const float*)d_in[3];
  float* out = (float*)d_out;

  char* ws = (char*)d_ws;
  u16* hbf = (u16*)ws;                                   // [0, 16M)
  char* sm = ws + (16u << 20);
  float* e1s = (float*)(sm);                             // 64 KB each
  float* e2s = (float*)(sm + (64u << 10));
  u32* permM = (u32*)(sm + (128u << 10));
  u32* kng = (u32*)(sm + (192u << 10));
  float* c1i = (float*)(sm + (256u << 10));
  float* c2i = (float*)(sm + (320u << 10));
  float* s1p = (float*)(sm + (512u << 10));              // 256 KB
  float* s2p = (float*)(sm + (768u << 10));              // 256 KB
  u16* wbt = (u16*)(sm + (1024u << 10));                 // 512 KB

  k_cast_wT<<<1024, 256, 0, stream>>>(W, wbt);
  k_gemm1<<<512, 256, 0, stream>>>(x, wbt, a, hbf, s1p, s2p);
  k_prep<<<16, 1024, 0, stream>>>(s1p, s2p, e1s, e2s, permM, kng, c1i, c2i);
  k_sweep2<<<1024, 256, 0, stream>>>(hbf, e1s, e2s, permM, kng, c1i, c2i, beta, out);
}

// Round 23
// 60.130 us; speedup vs baseline: 1.1818x; 1.0076x over previous
//
#include <hip/hip_runtime.h>

using u16 = unsigned short;
using u32 = unsigned int;
using u64 = unsigned long long;

#define ALPHA 0.2f
#define LOG2E 1.4426950408889634f

typedef __bf16 bf16x8 __attribute__((ext_vector_type(8)));
typedef float f32x4 __attribute__((ext_vector_type(4)));
typedef float f32x16 __attribute__((ext_vector_type(16)));

__device__ __forceinline__ u16 f2bf(float f) {
  u32 u = __builtin_bit_cast(u32, f);
  u += 0x7FFFu + ((u >> 16) & 1u);   // RTNE
  return (u16)(u >> 16);
}
__device__ __forceinline__ float bf2f(u16 h) {
  u32 u = ((u32)h) << 16;
  return __builtin_bit_cast(float, u);
}
__device__ __forceinline__ void gload_lds16(const void* g, void* l) {
  __builtin_amdgcn_global_load_lds((__attribute__((address_space(1))) void*)g,
                                   (__attribute__((address_space(3))) void*)l,
                                   16, 0, 0);
}

// ---------- cast+transpose W: wbt[n][k] = bf16(W[k][n]) ----------
__global__ __launch_bounds__(256) void k_cast_wT(const float* __restrict__ W, u16* __restrict__ wbt) {
  int idx = blockIdx.x * 256 + threadIdx.x;
  int k = idx >> 9, n = idx & 511;
  wbt[n * 512 + k] = f2bf(W[idx]);
}

// ---------- gemm1: h = x@W (M=16384,K=512,N=512). 128x128 tile, 4 waves.
// Triple-buffered, counted vmcnt, XCD-swizzled. Epilogue: hbf + score partials.
__global__ __launch_bounds__(256, 2) void k_gemm1(const float* __restrict__ x, const u16* __restrict__ wbt,
                                                  const float* __restrict__ a,
                                                  u16* __restrict__ hbf,
                                                  float* __restrict__ s1p, float* __restrict__ s2p) {
  __shared__ __attribute__((aligned(16))) char lds[73728];
  __shared__ __attribute__((aligned(16))) float a_l[256];

  const int t = threadIdx.x;
  const int lane = t & 63;
  const int w = t >> 6;
  const int l31 = lane & 31, lhi = lane >> 5;
  const int rb = w >> 1, cg = w & 1;
  const int g = blockIdx.x;
  const int cb = (g >> 3) & 3;
  const int tile_m = (g & 7) | ((g >> 5) << 3);
  const int row0 = tile_m * 128;
  const int col0 = cb * 128;

  a_l[t] = (t < 128) ? a[col0 + t] : a[512 + col0 + (t - 128)];

  f32x16 acc[2][2];
#pragma unroll
  for (int i = 0; i < 2; ++i)
#pragma unroll
    for (int j = 0; j < 2; ++j)
#pragma unroll
      for (int r = 0; r < 16; ++r) acc[i][j][r] = 0.f;

#define STAGE_G1(kt, Ab, Bb)                                                              \
  {                                                                                       \
    const int k0_ = (kt) * 32;                                                            \
    _Pragma("unroll")                                                                     \
    for (int i = 0; i < 4; ++i) {                                                         \
      int G = i * 256 + t;                                                                \
      int row = G >> 3, ks = G & 7;                                                       \
      gload_lds16(x + (size_t)(row0 + row) * 512 + k0_ + ((ks ^ (row & 7)) * 4),          \
                  (Ab) + (size_t)(i * 256 + w * 64) * 16);                                \
    }                                                                                     \
    _Pragma("unroll")                                                                     \
    for (int i = 0; i < 2; ++i) {                                                         \
      int G = i * 256 + t;                                                                \
      int col = G >> 2, ks = G & 3;                                                       \
      gload_lds16(wbt + (size_t)(col0 + col) * 512 + k0_ + ((ks ^ ((col >> 1) & 3)) * 8), \
                  (Bb) + (size_t)(i * 256 + w * 64) * 16);                                \
    }                                                                                     \
  }

#define COMPUTE_G1(Ab, Bb)                                                                         \
  {                                                                                                \
    _Pragma("unroll")                                                                              \
    for (int ks = 0; ks < 2; ++ks) {                                                               \
      bf16x8 af[2];                                                                                \
      _Pragma("unroll")                                                                            \
      for (int sub = 0; sub < 2; ++sub) {                                                          \
        const int arow = rb * 64 + sub * 32 + l31;                                                 \
        const int kg = ks * 4 + lhi * 2;                                                           \
        f32x4 fa0 = *reinterpret_cast<const f32x4*>((Ab) + (size_t)(arow * 8 + (kg ^ (arow & 7))) * 16); \
        f32x4 fa1 = *reinterpret_cast<const f32x4*>((Ab) + (size_t)(arow * 8 + ((kg + 1) ^ (arow & 7))) * 16); \
        _Pragma("unroll")                                                                          \
        for (int jj = 0; jj < 4; ++jj) {                                                           \
          af[sub][jj] = (__bf16)fa0[jj];                                                           \
          af[sub][jj + 4] = (__bf16)fa1[jj];                                                       \
        }                                                                                          \
      }                                                                                            \
      bf16x8 bfr[2];                                                                               \
      _Pragma("unroll")                                                                            \
      for (int bt = 0; bt < 2; ++bt) {                                                             \
        const int bcol = cg * 64 + bt * 32 + l31;                                                  \
        const int kslot = (ks * 2 + lhi) ^ ((bcol >> 1) & 3);                                      \
        bfr[bt] = *reinterpret_cast<const bf16x8*>((Bb) + (size_t)(bcol * 4 + kslot) * 16);        \
      }                                                                                            \
      _Pragma("unroll")                                                                            \
      for (int sub = 0; sub < 2; ++sub)                                                            \
        _Pragma("unroll")                                                                          \
        for (int bt = 0; bt < 2; ++bt)                                                             \
          acc[sub][bt] = __builtin_amdgcn_mfma_f32_32x32x16_bf16(af[sub], bfr[bt], acc[sub][bt], 0, 0, 0); \
    }                                                                                              \
  }

  char* Ac = lds;             char* Bc = lds + 49152;
  char* An = lds + 16384;     char* Bn = lds + 57344;
  char* As = lds + 32768;     char* Bs = lds + 65536;

  STAGE_G1(0, Ac, Bc);
  STAGE_G1(1, An, Bn);
  __builtin_amdgcn_sched_barrier(0);
  asm volatile("s_waitcnt vmcnt(6) lgkmcnt(0)" ::: "memory");
  __builtin_amdgcn_s_barrier();
  __builtin_amdgcn_sched_barrier(0);

#pragma unroll 1
  for (int kt = 0; kt < 14; ++kt) {
    STAGE_G1(kt + 2, As, Bs);
    COMPUTE_G1(Ac, Bc);
    __builtin_amdgcn_sched_barrier(0);
    asm volatile("s_waitcnt vmcnt(6)" ::: "memory");
    __builtin_amdgcn_s_barrier();
    __builtin_amdgcn_sched_barrier(0);
    char* ta = Ac; Ac = An; An = As; As = ta;
    char* tb = Bc; Bc = Bn; Bn = Bs; Bs = tb;
  }
  COMPUTE_G1(Ac, Bc);
  __builtin_amdgcn_sched_barrier(0);
  asm volatile("s_waitcnt vmcnt(0)" ::: "memory");
  __builtin_amdgcn_s_barrier();
  __builtin_amdgcn_sched_barrier(0);
  COMPUTE_G1(An, Bn);
#undef STAGE_G1
#undef COMPUTE_G1

  __syncthreads();

  u16* lT = (u16*)lds;
#pragma unroll
  for (int sub = 0; sub < 2; ++sub)
#pragma unroll
    for (int bt = 0; bt < 2; ++bt) {
      const int col = cg * 64 + bt * 32 + l31;
#pragma unroll
      for (int r = 0; r < 16; ++r) {
        int row = rb * 64 + sub * 32 + (r & 3) + 8 * (r >> 2) + 4 * lhi;
        lT[row * 136 + col] = f2bf(acc[sub][bt][r]);
      }
    }
  __syncthreads();

#pragma unroll
  for (int i = 0; i < 8; ++i) {
    int G = i * 256 + t;
    int row = G >> 4, gg = G & 15;
    uint4 v = *reinterpret_cast<const uint4*>(&lT[row * 136 + gg * 8]);
    *reinterpret_cast<uint4*>(&hbf[(size_t)(row0 + row) * 512 + col0 + gg * 8]) = v;
  }
  {
    const int r2 = t >> 1, half = t & 1;
    float d1 = 0.f, d2 = 0.f;
#pragma unroll
    for (int i = 0; i < 8; ++i) {
      uint4 v = *reinterpret_cast<const uint4*>(&lT[r2 * 136 + half * 64 + i * 8]);
      u32 wds[4] = {v.x, v.y, v.z, v.w};
#pragma unroll
      for (int jj = 0; jj < 8; ++jj) {
        float h = bf2f((u16)(wds[jj >> 1] >> ((jj & 1) * 16)));
        d1 += h * a_l[half * 64 + i * 8 + jj];
        d2 += h * a_l[128 + half * 64 + i * 8 + jj];
      }
    }
    d1 += __shfl_xor(d1, 1);
    d2 += __shfl_xor(d2, 1);
    if (half == 0) {
      s1p[cb * 16384 + row0 + r2] = d1;
      s2p[cb * 16384 + row0 + r2] = d2;
    }
  }
}

// ---------- prep: reduce partials; hybrid shfl/LDS bitonic sort; wave-shfl scans;
// exact denominators folded into c1i/c2i; kn. ----------
__global__ __launch_bounds__(1024) void k_prep(const float* __restrict__ s1p, const float* __restrict__ s2p,
                                               float* __restrict__ e1s, float* __restrict__ e2s,
                                               u32* __restrict__ permM, u32* __restrict__ kng,
                                               float* __restrict__ c1ig, float* __restrict__ c2ig) {
  __shared__ u32 sk[1024];
  __shared__ float s2all[1024];
  __shared__ float s2sv[1024];
  __shared__ float arrA[1024];
  __shared__ float arrB[1024];
  __shared__ float wtA[16], wtB[16];
  const int b = blockIdx.x;
  const int t = threadIdx.x;
  const int lane = t & 63, wid = t >> 6;
  const int id = b * 1024 + t;

  const float s1v = (s1p[id] + s1p[16384 + id] + s1p[32768 + id] + s1p[49152 + id]) * LOG2E;
  const float s2v = (s2p[id] + s2p[16384 + id] + s2p[32768 + id] + s2p[49152 + id]) * LOG2E;
  s2all[t] = s2v;

  u32 key;
  {
    u32 bits = __builtin_bit_cast(u32, s2v);
    u32 k2 = (bits & 0x80000000u) ? ~bits : (bits | 0x80000000u);
    key = (k2 & 0xFFFFFC00u) | (u32)t;   // truncated key | idx
  }

#define SHFL_CE(size_, stride_)                                            \
  {                                                                        \
    u32 partner = (u32)__shfl_xor((int)key, (stride_));                    \
    bool dir = ((t & (size_)) == 0);                                       \
    bool keepMin = (dir == ((t & (stride_)) == 0));                        \
    key = keepMin ? (key < partner ? key : partner)                        \
                  : (key > partner ? key : partner);                       \
  }

#pragma unroll
  for (int size = 2; size <= 64; size <<= 1)
#pragma unroll
    for (int stride = size >> 1; stride > 0; stride >>= 1) SHFL_CE(size, stride);

#pragma unroll 1
  for (int size = 128; size <= 1024; size <<= 1) {
    sk[t] = key;
#pragma unroll 1
    for (int stride = size >> 1; stride >= 64; stride >>= 1) {
      __syncthreads();
      int ixj = t ^ stride;
      if (ixj > t) {
        u32 va = sk[t], vb = sk[ixj];
        bool asc = ((t & size) == 0);
        if ((va > vb) == asc) { sk[t] = vb; sk[ixj] = va; }
      }
    }
    __syncthreads();
    key = sk[t];
#pragma unroll
    for (int stride = 32; stride > 0; stride >>= 1) SHFL_CE(size, stride);
  }
#undef SHFL_CE

  const u32 idx = key & 1023u;
  const float sv = s2all[idx];
  s2sv[t] = sv;
  __syncthreads();

  const float E1 = exp2f(sv), E2 = exp2f(ALPHA * sv);
  e1s[b * 1024 + t] = E1;
  e2s[b * 1024 + t] = E2;
  permM[b * 1024 + t] = idx;

  float aA = E2;
  float aB = exp2f(s2sv[1023 - t]);
#pragma unroll
  for (int off = 1; off < 64; off <<= 1) {
    float uA = __shfl_up(aA, off);
    float uB = __shfl_up(aB, off);
    if (lane >= off) { aA += uA; aB += uB; }
  }
  if (lane == 63) { wtA[wid] = aA; wtB[wid] = aB; }
  __syncthreads();
  {
    float offA = 0.f, offB = 0.f;
#pragma unroll
    for (int i2 = 0; i2 < 16; ++i2) {
      float vA2 = wtA[i2], vB2 = wtB[i2];
      if (i2 < wid) { offA += vA2; offB += vB2; }
    }
    aA += offA;
    aB += offB;
  }
  arrA[t] = aA;
  arrB[t] = aB;
  __syncthreads();

  {
    const float thr = -s1v;
    int lo = 0, hi = 1024;
    while (lo < hi) { int mid = (lo + hi) >> 1; if (s2sv[mid] <= thr) lo = mid + 1; else hi = mid; }
    const int kn = lo;
    float se1suf = (kn == 1024) ? 0.f : arrB[1023 - kn];
    float se2pre = (kn == 0) ? 0.f : arrA[kn - 1];
    const float c1 = exp2f(s1v), c2 = exp2f(ALPHA * s1v);
    const float inv = 1.0f / (c1 * se1suf + c2 * se2pre);
    c1ig[id] = c1 * inv;
    c2ig[id] = c2 * inv;
    kng[id] = (u32)kn;
  }
}

// ---------- sweep2: per (b, 8-f chunk), 256 thr = 32 segs x 8 f. Per-element
// packed scan table Cp[phys(i)][8], phys(i)=i+(i>>5). ~38KB LDS -> 4 blocks/CU.
// Phase 2: wave covers 8 consecutive n x 8 f -> 8 lines/instr (4x fewer TA slots). ----------
__global__ __launch_bounds__(256, 4) void k_sweep2(const u16* __restrict__ hbf,
                                                   const float* __restrict__ e1s, const float* __restrict__ e2s,
                                                   const u32* __restrict__ permM, const u32* __restrict__ kng,
                                                   const float* __restrict__ c1ig, const float* __restrict__ c2ig,
                                                   const float* __restrict__ betag, float* __restrict__ out) {
  __shared__ u32 Cp[1060][8];      // phys rows: 1024 + 32 pads + sentinel(1056)
  __shared__ u16 kn_l[1024];
  __shared__ float segS1[32][8];
  __shared__ float segP2[32][8];

  const int t = threadIdx.x;
  const int B = blockIdx.x;
  const int b = (B & 7) * 2 + ((B >> 3) & 1);   // XCD swizzle: batch's 64 blocks share an XCD
  const int fc = B >> 4;                         // 0..63 : 8-f chunk

  const u16* hB = hbf + (size_t)b * 1024 * 512 + fc * 8;

#pragma unroll
  for (int q = 0; q < 4; ++q) {
    int i = q * 256 + t;
    kn_l[i] = (u16)kng[b * 1024 + i];
  }

  // phase 1: thread (seg=t>>3, f=t&7) owns sorted positions [seg*32, seg*32+32)
  const int f = t & 7;
  const int seg = t >> 3;          // 0..31
  const int i0 = seg * 32;
  const int p0 = seg * 33;         // phys base: i + (i>>5)
  const u32* permB = permM + b * 1024 + i0;
  const float* e1B = e1s + b * 1024 + i0;
  const float* e2B = e2s + b * 1024 + i0;

  // pass A: gather 32 sorted h values (packed pairs) + per-seg totals
  u32 hpk[16];
  float ss1 = 0.f, ss2 = 0.f;
#pragma unroll
  for (int c = 0; c < 32; c += 2) {
    u16 h0 = hB[(size_t)permB[c] * 512 + f];
    u16 h1 = hB[(size_t)permB[c + 1] * 512 + f];
    hpk[c >> 1] = (u32)h0 | ((u32)h1 << 16);
    ss1 = fmaf(e1B[c], bf2f(h0), ss1);
    ss1 = fmaf(e1B[c + 1], bf2f(h1), ss1);
    ss2 = fmaf(e2B[c], bf2f(h0), ss2);
    ss2 = fmaf(e2B[c + 1], bf2f(h1), ss2);
  }
  segS1[seg][f] = ss1;
  segP2[seg][f] = ss2;
  __syncthreads();

  float sufAfter = 0.f, preBefore = 0.f;
#pragma unroll
  for (int s7 = 0; s7 < 32; ++s7) {
    if (s7 > seg) sufAfter += segS1[s7][f];
    if (s7 < seg) preBefore += segP2[s7][f];
  }

  // pass B: backward walk -> packed bf16 suffix values in 16 regs
  u32 c1p[16];
  {
    float run1 = sufAfter;
#pragma unroll
    for (int c = 31; c >= 0; --c) {
      u16 hv = (u16)(hpk[c >> 1] >> ((c & 1) * 16));
      run1 = fmaf(e1B[c], bf2f(hv), run1);
      if (c & 1) c1p[c >> 1] = (u32)f2bf(run1) << 16;
      else c1p[c >> 1] |= (u32)f2bf(run1);
    }
  }
  // pass C: forward walk -> packed (suffix | excl-prefix) store
  {
    float run2 = preBefore;
#pragma unroll
    for (int c = 0; c < 32; ++c) {
      u16 c1v = (u16)(c1p[c >> 1] >> ((c & 1) * 16));
      Cp[p0 + c][f] = (u32)c1v | ((u32)f2bf(run2) << 16);
      u16 hv = (u16)(hpk[c >> 1] >> ((c & 1) * 16));
      run2 = fmaf(e2B[c], bf2f(hv), run2);
    }
    if (seg == 31) Cp[1056][f] = (u32)f2bf(run2) << 16;   // kn=1024 sentinel
  }
  __syncthreads();

  // phase 2: wave covers n in [r*32+wv*8, +8) x f 0..8 -> 8-line loads/stores
  const float beta = betag[0];
  const int nn = (t >> 3) & 7;     // n within 8-group
  const int wv = t >> 6;           // wave id 0..3
  const float* c1B = c1ig + b * 1024;
  const float* c2B = c2ig + b * 1024;
#pragma unroll 4
  for (int r = 0; r < 32; ++r) {
    const int n = r * 32 + wv * 8 + nn;
    const int kn = (int)kn_l[n];
    const u32 cp = Cp[kn + (kn >> 5)][f];
    const float A = bf2f((u16)(cp & 0xFFFFu));
    const float Bv = bf2f((u16)(cp >> 16));
    const float hvn = bf2f(hB[(size_t)n * 512 + f]);
    const float xv = c1B[n] * A + c2B[n] * Bv + beta * hvn;
    out[((size_t)b * 1024 + n) * 512 + fc * 8 + f] = xv > 0.f ? xv : __expf(xv) - 1.0f;
  }
}

extern "C" void kernel_launch(void* const* d_in, const int* in_sizes, int n_in,
                              void* d_out, int out_size, void* d_ws, size_t ws_size,
                              hipStream_t stream) {
  const float* x = (const float*)d_in[0];
  const float* W = (const float*)d_in[1];
  const float* a = (const float*)d_in[2];
  const float* beta = (const float*)d_in[3];
  float* out = (float*)d_out;

  char* ws = (char*)d_ws;
  u16* hbf = (u16*)ws;                                   // [0, 16M)
  char* sm = ws + (16u << 20);
  float* e1s = (float*)(sm);                             // 64 KB each
  float* e2s = (float*)(sm + (64u << 10));
  u32* permM = (u32*)(sm + (128u << 10));
  u32* kng = (u32*)(sm + (192u << 10));
  float* c1i = (float*)(sm + (256u << 10));
  float* c2i = (float*)(sm + (320u << 10));
  float* s1p = (float*)(sm + (512u << 10));              // 256 KB
  float* s2p = (float*)(sm + (768u << 10));              // 256 KB
  u16* wbt = (u16*)(sm + (1024u << 10));                 // 512 KB

  k_cast_wT<<<1024, 256, 0, stream>>>(W, wbt);
  k_gemm1<<<512, 256, 0, stream>>>(x, wbt, a, hbf, s1p, s2p);
  k_prep<<<16, 1024, 0, stream>>>(s1p, s2p, e1s, e2s, permM, kng, c1i, c2i);
  k_sweep2<<<1024, 256, 0, stream>>>(hbf, e1s, e2s, permM, kng, c1i, c2i, beta, out);
}